// Round 5
// baseline (292.680 us; speedup 1.0000x reference)
//
#include <hip/hip_runtime.h>

// TensorConvolutionTrainLayer: S=512,P=196,Q=48,CB=8,R=32,C=10,N=8
// R5: chain holds the whole per-step A-slice (64x224) in 112 VGPRs per wave —
// Ash/LDS-staging deleted (was 1.8MB/CU/step of redundant LDS reads). G-phase is
// pure register MFMA; Gsh round-trip + MFMA state update (R4) unchanged.

typedef _Float16 half8 __attribute__((ext_vector_type(8)));
typedef _Float16 half4 __attribute__((ext_vector_type(4)));
typedef float floatx4 __attribute__((ext_vector_type(4)));

#define KP 224    // P padded to 7*32
#define QP 64     // Q padded to 2*32
#define LDA2 232  // Mt2 row stride (halfs)
#define GSTR 40   // Gsh row stride (halfs): 20 dwords -> good bank spread
#define SSTR 264  // St3 row stride (halfs)

__device__ __forceinline__ void gld_lds16(const void* g, void* l) {
  __builtin_amdgcn_global_load_lds((const __attribute__((address_space(1))) void*)g,
                                   (__attribute__((address_space(3))) void*)l, 16, 0, 0);
}

// ---------------- generic MFMA GEMM (unchanged) ----------------
template<int K, int MODE>
__global__ __launch_bounds__(256)
void gemm_mfma(const _Float16* __restrict__ A, const _Float16* __restrict__ Bt,
               void* __restrict__ out0, void* __restrict__ out1, void* __restrict__ out2)
{
  __shared__ __align__(16) _Float16 Ash[128 * 32];
  __shared__ __align__(16) _Float16 Bsh[128 * 32];
  const int tid  = threadIdx.x;
  const int wave = tid >> 6;
  const int lane = tid & 63;
  const int m0 = blockIdx.y * 128;
  const int n0 = blockIdx.x * 128;
  const int wm = (wave >> 1) * 64;
  const int wn = (wave & 1) * 64;
  const int fr = lane & 15;
  const int fq = lane >> 4;

  floatx4 acc[4][4] = {};

  for (int kt = 0; kt < K; kt += 32) {
    __syncthreads();
#pragma unroll
    for (int j = 0; j < 2; j++) {
      const int c   = j * 256 + tid;
      const int row = c >> 2;
      const int ko  = (c & 3) * 8;
      gld_lds16(A  + (size_t)(m0 + row) * K + kt + ko,
                (char*)Ash + (size_t)(j * 256 + wave * 64) * 16);
      gld_lds16(Bt + (size_t)(n0 + row) * K + kt + ko,
                (char*)Bsh + (size_t)(j * 256 + wave * 64) * 16);
    }
    __syncthreads();
    half8 af[4], bf[4];
#pragma unroll
    for (int i = 0; i < 4; i++)
      af[i] = *(const half8*)&Ash[(wm + i * 16 + fr) * 32 + fq * 8];
#pragma unroll
    for (int i = 0; i < 4; i++)
      bf[i] = *(const half8*)&Bsh[(wn + i * 16 + fr) * 32 + fq * 8];
#pragma unroll
    for (int i = 0; i < 4; i++)
#pragma unroll
      for (int j = 0; j < 4; j++)
        acc[i][j] = __builtin_amdgcn_mfma_f32_16x16x32_f16(af[i], bf[j], acc[i][j], 0, 0, 0);
  }

#pragma unroll
  for (int i = 0; i < 4; i++) {
#pragma unroll
    for (int j = 0; j < 4; j++) {
#pragma unroll
      for (int r = 0; r < 4; r++) {
        const int m = m0 + wm + i * 16 + fq * 4 + r;
        const int n = n0 + wn + j * 16 + fr;
        const float v = acc[i][j][r];
        if constexpr (MODE == 0) {
          const unsigned s = (unsigned)n / 196u;
          const unsigned p = (unsigned)n - s * 196u;
          if (m < 8)
            ((_Float16*)out1)[((size_t)m * 512 + s) * KP + p] = (_Float16)v;
          else if (m < 392)
            ((_Float16*)out0)[((size_t)s * 384 + (m - 8)) * LDA2 + p] = (_Float16)v;
          else if (m < 400)
            ((_Float16*)out2)[((size_t)(m - 392) * 512 + s) * KP + p] = (_Float16)v;
        } else if constexpr (MODE == 2) {
          if (n < 320)
            ((float*)out0)[(size_t)(m & 511) * 2560 + (m >> 9) * 320 + n] = v;
        } else {
          if (n < 32)
            ((float*)out0)[(size_t)m * 32 + n] = v;
        }
      }
    }
  }
}

// ---------------- fused chain kernel ----------------
__global__ __launch_bounds__(256, 2)
void chain_kernel(const _Float16* __restrict__ Mt2, const _Float16* __restrict__ Akr,
                  const float* __restrict__ St0, const float* __restrict__ GN,
                  float* __restrict__ out)
{
  __shared__ __align__(16) _Float16 Gsh[2][256 * GSTR];    // 40960 B
  __shared__ __align__(16) _Float16 St3[16 * SSTR];        // 8448 B
  __shared__ float oc[10];

  const int tid  = threadIdx.x;
  const int wave = tid >> 6;
  const int lane = tid & 63;
  const int s    = blockIdx.x;
  const int fr   = lane & 15;
  const int fq   = lane >> 4;
  const int fqh  = fq >> 1;
  const int fql  = fq & 1;

  // init: St3[c][r*8+sigma(b)] from St0[s][b*320+r*10+c]; tid=(b,r)
  {
    const int b = tid >> 5, r = tid & 31;
    const int kcol = r * 8 + ((b & 1) * 4 + (b >> 1));
    const float* src = St0 + (size_t)s * 2560 + (size_t)tid * 10;
#pragma unroll
    for (int c = 0; c < 10; c++) St3[c * SSTR + kcol] = (_Float16)src[c];
    if (tid < 10) oc[tid] = 0.f;
  }

  // A-slice for step 0: whole 64x224 tile in registers (MFMA A-layout)
  half8 af[7][4];
  {
    const _Float16* Ab = Mt2 + (size_t)s * 384 * LDA2;
#pragma unroll
    for (int kt = 0; kt < 7; kt++)
#pragma unroll
      for (int mi = 0; mi < 4; mi++)
        af[kt][mi] = *(const half8*)(Ab + (size_t)(mi * 16 + fr) * LDA2 + kt * 32 + fq * 8);
  }
  // B fragments for (k=0, cc=0)
  half8 bf[7][2];
  {
    const _Float16* Bb = Akr + (size_t)(wave * 32) * KP;
#pragma unroll
    for (int kt = 0; kt < 7; kt++)
#pragma unroll
      for (int ni = 0; ni < 2; ni++)
        bf[kt][ni] = *(const half8*)(Bb + (size_t)(ni * 16 + fr) * KP + kt * 32 + fq * 8);
  }
  __syncthreads();   // St3 visible to all waves

  for (int k = 0; k < 6; k++) {
    floatx4 ns[4] = {};

    for (int cc = 0; cc < 8; cc++) {
      // ---- G-phase: pure register MFMA ----
      floatx4 acc[4][2] = {};
#pragma unroll
      for (int kt = 0; kt < 7; kt++)
#pragma unroll
        for (int mi = 0; mi < 4; mi++)
#pragma unroll
          for (int ni = 0; ni < 2; ni++)
            acc[mi][ni] = __builtin_amdgcn_mfma_f32_16x16x32_f16(af[kt][mi], bf[kt][ni], acc[mi][ni], 0, 0, 0);

      // af's last use this step was cc=7: reload next step's A-slice now
      if (cc == 7 && k < 5) {
        const _Float16* Ab = Mt2 + ((size_t)s * 384 + 64 * (k + 1)) * LDA2;
#pragma unroll
        for (int kt = 0; kt < 7; kt++)
#pragma unroll
          for (int mi = 0; mi < 4; mi++)
            af[kt][mi] = *(const half8*)(Ab + (size_t)(mi * 16 + fr) * LDA2 + kt * 32 + fq * 8);
      }
      // prefetch next B fragments (covered by cvt+write+barrier+NS)
      {
        int ncc = cc + 1, nk = k;
        if (ncc == 8) { ncc = 0; nk = k + 1; }
        if (nk < 6) {
          const _Float16* Bn = Akr + ((size_t)nk * 1024 + ncc * 128 + wave * 32) * KP;
#pragma unroll
          for (int kt = 0; kt < 7; kt++)
#pragma unroll
            for (int ni = 0; ni < 2; ni++)
              bf[kt][ni] = *(const half8*)(Bn + (size_t)(ni * 16 + fr) * KP + kt * 32 + fq * 8);
        }
      }
      // cvt: pack 4 mi-values (k'-contiguous under sigma) per (ni,rg)
      half4 gh[2][4];
#pragma unroll
      for (int ni = 0; ni < 2; ni++)
#pragma unroll
        for (int rg = 0; rg < 4; rg++)
#pragma unroll
          for (int mi = 0; mi < 4; mi++)
            gh[ni][rg][mi] = (_Float16)acc[mi][ni][rg];
      // write Gsh[cc&1]: row m=(b,r), k' = wave*8 + fqh*4 + mi
      {
        _Float16* gb = &Gsh[cc & 1][0];
#pragma unroll
        for (int ni = 0; ni < 2; ni++)
#pragma unroll
          for (int rg = 0; rg < 4; rg++) {
            const int m = (fql * 4 + rg) * 32 + ni * 16 + fr;
            *(half4*)&gb[m * GSTR + wave * 8 + fqh * 4] = gh[ni][rg];
          }
      }
      __syncthreads();   // Gsh[cc&1] visible
      // ---- NS-phase: NS[m][c] += G[m][k-slice] * St3[c][k-slice] ----
      {
        const _Float16* gb = &Gsh[cc & 1][0];
        const half8 bs = *(const half8*)&St3[fr * SSTR + cc * 32 + fq * 8];
#pragma unroll
        for (int t = 0; t < 4; t++) {
          const half8 aa = *(const half8*)&gb[((wave * 4 + t) * 16 + fr) * GSTR + fq * 8];
          ns[t] = __builtin_amdgcn_mfma_f32_16x16x32_f16(aa, bs, ns[t], 0, 0, 0);
        }
      }
    }

    __syncthreads();   // all NS reads of St3 done before overwrite
    // epilogue: NS -> St3 (next step's B operand). m=(b,r): k_next = r*8+sigma(b)
    if (fr < 10) {
#pragma unroll
      for (int t = 0; t < 4; t++) {
#pragma unroll
        for (int rg = 0; rg < 4; rg++) {
          const int m = (wave * 4 + t) * 16 + fq * 4 + rg;
          const int b = m >> 5, r = m & 31;
          St3[fr * SSTR + r * 8 + ((b & 1) * 4 + (b >> 1))] = (_Float16)ns[t][rg];
        }
      }
    }
    // next iteration's cc=0 barrier orders these writes before any NS read
  }
  __syncthreads();

  // final: out[s,c] = sum_{a,l} St3[c][l*8+sigma(a)] * GN[a][s][l]
  {
    const int a = tid >> 5, l = tid & 31;
    const float gn = GN[((size_t)a * 512 + s) * 32 + l];
    const int kcol = l * 8 + ((a & 1) * 4 + (a >> 1));
#pragma unroll
    for (int c = 0; c < 10; c++) {
      float v = gn * (float)St3[c * SSTR + kcol];
#pragma unroll
      for (int o2 = 1; o2 < 64; o2 <<= 1) v += __shfl_xor(v, o2, 64);
      if (lane == 0) atomicAdd(&oc[c], v);
    }
    __syncthreads();
    if (tid < 10) out[(size_t)s * 10 + tid] = oc[tid];
  }
}

// ---------------- prep kernels ----------------
__global__ void prep_xh(const float* __restrict__ x, _Float16* __restrict__ xh) {
  const int idx = blockIdx.x * 256 + threadIdx.x;
  const int q = idx & 63, sp = idx >> 6;
  xh[idx] = (q < 48) ? (_Float16)x[sp * 48 + q] : (_Float16)0.f;
}

// merged small preps: Ckt [0,32768) | Akr [32768,1409024) | Bt0 [...,1495040) | Btl [...,1523712)
__global__ void prep_small(const float* __restrict__ cf, const float* __restrict__ cm,
                           const float* __restrict__ cl, const float* __restrict__ tf,
                           const float* __restrict__ tm, const float* __restrict__ tl,
                           _Float16* __restrict__ Ckt, _Float16* __restrict__ Akr,
                           _Float16* __restrict__ Bt0, _Float16* __restrict__ Btl) {
  const int idx = blockIdx.x * 256 + threadIdx.x;
  if (idx < 32768) {
    const int q = idx & 63;
    const int row = idx >> 6;
    float v = 0.f;
    if (q < 48) {
      if (row < 8) v = cf[q * 8 + row];
      else if (row < 392) {
        const int rr = row - 8;
        const int k = rr >> 6, ab = rr & 63, a = ab >> 3, b = ab & 7;
        v = cm[((k * 8 + a) * 48 + q) * 8 + b];
      } else if (row < 400) v = cl[(row - 392) * 48 + q];
    }
    Ckt[idx] = (_Float16)v;
  } else if (idx < 1409024) {
    const int i2 = idx - 32768;
    const int p = i2 % 224;
    const int lr = (i2 / 224) & 1023;
    const int k = i2 / (224 * 1024);
    const int l = lr >> 5, r = lr & 31;
    float v = 0.f;
    if (p < 196) v = tm[(((k * 32 + l) * 196) + p) * 32 + r];
    Akr[i2] = (_Float16)v;
  } else if (idx < 1495040) {
    const int i2 = idx - 1409024;
    const int p = i2 % 224;
    const int n = i2 / 224;
    float v = 0.f;
    if (n < 320 && p < 196) {
      const int r = n / 10, c = n % 10;
      v = tf[(c * 196 + p) * 32 + r];
    }
    Bt0[i2] = (_Float16)v;
  } else {
    const int i2 = idx - 1495040;
    const int p = i2 % 224;
    const int n = i2 / 224;
    float v = 0.f;
    if (n < 32 && p < 196) v = tl[n * 196 + p];
    Btl[i2] = (_Float16)v;
  }
}

__global__ void zero_pads(_Float16* __restrict__ Mt2, _Float16* __restrict__ MtF,
                          _Float16* __restrict__ MtL) {
  const int idx = blockIdx.x * 256 + threadIdx.x;
  if (idx < 196608) {
    _Float16* p = Mt2 + (size_t)idx * LDA2 + 196;
#pragma unroll
    for (int j = 0; j < 36; j++) p[j] = (_Float16)0.f;
  }
  if (idx < 4096) {
    _Float16* p = MtF + (size_t)idx * KP + 196;
    _Float16* q = MtL + (size_t)idx * KP + 196;
#pragma unroll
    for (int j = 0; j < 28; j++) { p[j] = (_Float16)0.f; q[j] = (_Float16)0.f; }
  }
}

extern "C" void kernel_launch(void* const* d_in, const int* in_sizes, int n_in,
                              void* d_out, int out_size, void* d_ws, size_t ws_size,
                              hipStream_t stream)
{
  const float* x  = (const float*)d_in[0];
  const float* cf = (const float*)d_in[1];
  const float* cm = (const float*)d_in[2];
  const float* cl = (const float*)d_in[3];
  const float* tf = (const float*)d_in[4];
  const float* tm = (const float*)d_in[5];
  const float* tl = (const float*)d_in[6];
  float* out = (float*)d_out;

  char* w = (char*)d_ws;
  auto alloc = [&](size_t bytes) { char* p = w; w += (bytes + 255) & ~(size_t)255; return p; };
  _Float16* xh  = (_Float16*)alloc(100352ull * 64 * 2);
  _Float16* Ckt = (_Float16*)alloc(512ull * 64 * 2);
  _Float16* Mt2 = (_Float16*)alloc(512ull * 384 * LDA2 * 2);
  _Float16* MtF = (_Float16*)alloc(8ull * 512 * KP * 2);
  _Float16* MtL = (_Float16*)alloc(8ull * 512 * KP * 2);
  _Float16* Akr = (_Float16*)alloc(6ull * 1024 * KP * 2);
  _Float16* Bt0 = (_Float16*)alloc(384ull * KP * 2);
  _Float16* Btl = (_Float16*)alloc(128ull * KP * 2);
  float* stA    = (float*)alloc(512ull * 2560 * 4);
  float* GN     = (float*)alloc(4096ull * 32 * 4);
  (void)ws_size; (void)in_sizes; (void)n_in; (void)out_size;

  prep_xh   <<<25088, 256, 0, stream>>>(x, xh);
  prep_small<<< 5952, 256, 0, stream>>>(cf, cm, cl, tf, tm, tl, Ckt, Akr, Bt0, Btl);
  zero_pads <<<  768, 256, 0, stream>>>(Mt2, MtF, MtL);

  gemm_mfma<QP, 0><<<dim3(784, 4), 256, 0, stream>>>(Ckt, xh, Mt2, MtF, MtL);
  gemm_mfma<KP, 2><<<dim3(3, 32), 256, 0, stream>>>(MtF, Bt0, stA, nullptr, nullptr);
  gemm_mfma<KP, 3><<<dim3(1, 32), 256, 0, stream>>>(MtL, Btl, GN, nullptr, nullptr);

  chain_kernel<<<512, 256, 0, stream>>>(Mt2, Akr, stA, GN, out);
}

// Round 6
// 274.752 us; speedup vs baseline: 1.0653x; 1.0653x over previous
//
#include <hip/hip_runtime.h>

// TensorConvolutionTrainLayer: S=512,P=196,Q=48,CB=8,R=32,C=10,N=8
// R6: chain A-operand stored fragment-major in global ([s][k][frag][lane][8]) so
// staging is fully-coalesced gld_lds and every af LDS read is a lane-contiguous
// conflict-free ds_read_b128. Wave owns 64 lr cols (ni=4, cc=4): halves Ash
// re-reads vs R4. bf is a 2-deep kt ring (32 VGPRs) -> fits 128-VGPR cap, no
// spills (R5 post-mortem: WRITE_SIZE is the spill detector).

typedef _Float16 half8 __attribute__((ext_vector_type(8)));
typedef _Float16 half4 __attribute__((ext_vector_type(4)));
typedef float floatx4 __attribute__((ext_vector_type(4)));

#define KP 224     // P padded to 7*32
#define QP 64      // Q padded to 2*32
#define GSTR2 72   // Gsh row stride (halfs): 144B = 9x16B, conflict-free
#define SSTR 264   // St3 row stride (halfs): 528B
#define SLICE 14336 // per-(s,k) A slice: 28 frags * 64 lanes * 8 halfs

__device__ __forceinline__ void gld_lds16(const void* g, void* l) {
  __builtin_amdgcn_global_load_lds((const __attribute__((address_space(1))) void*)g,
                                   (__attribute__((address_space(3))) void*)l, 16, 0, 0);
}

// ---------------- generic MFMA GEMM ----------------
// MODE0 epilogue: mid rows -> Mt3 fragment-major; first/last -> MtF/MtL.
template<int K, int MODE>
__global__ __launch_bounds__(256)
void gemm_mfma(const _Float16* __restrict__ A, const _Float16* __restrict__ Bt,
               void* __restrict__ out0, void* __restrict__ out1, void* __restrict__ out2)
{
  __shared__ __align__(16) _Float16 Ash[128 * 32];
  __shared__ __align__(16) _Float16 Bsh[128 * 32];
  const int tid  = threadIdx.x;
  const int wave = tid >> 6;
  const int lane = tid & 63;
  const int m0 = blockIdx.y * 128;
  const int n0 = blockIdx.x * 128;
  const int wm = (wave >> 1) * 64;
  const int wn = (wave & 1) * 64;
  const int fr = lane & 15;
  const int fq = lane >> 4;

  floatx4 acc[4][4] = {};

  for (int kt = 0; kt < K; kt += 32) {
    __syncthreads();
#pragma unroll
    for (int j = 0; j < 2; j++) {
      const int c   = j * 256 + tid;
      const int row = c >> 2;
      const int ko  = (c & 3) * 8;
      gld_lds16(A  + (size_t)(m0 + row) * K + kt + ko,
                (char*)Ash + (size_t)(j * 256 + wave * 64) * 16);
      gld_lds16(Bt + (size_t)(n0 + row) * K + kt + ko,
                (char*)Bsh + (size_t)(j * 256 + wave * 64) * 16);
    }
    __syncthreads();
    half8 af[4], bf[4];
#pragma unroll
    for (int i = 0; i < 4; i++)
      af[i] = *(const half8*)&Ash[(wm + i * 16 + fr) * 32 + fq * 8];
#pragma unroll
    for (int i = 0; i < 4; i++)
      bf[i] = *(const half8*)&Bsh[(wn + i * 16 + fr) * 32 + fq * 8];
#pragma unroll
    for (int i = 0; i < 4; i++)
#pragma unroll
      for (int j = 0; j < 4; j++)
        acc[i][j] = __builtin_amdgcn_mfma_f32_16x16x32_f16(af[i], bf[j], acc[i][j], 0, 0, 0);
  }

#pragma unroll
  for (int i = 0; i < 4; i++) {
#pragma unroll
    for (int j = 0; j < 4; j++) {
#pragma unroll
      for (int r = 0; r < 4; r++) {
        const int m = m0 + wm + i * 16 + fq * 4 + r;
        const int n = n0 + wn + j * 16 + fr;
        const float v = acc[i][j][r];
        if constexpr (MODE == 0) {
          const unsigned s = (unsigned)n / 196u;
          const unsigned p = (unsigned)n - s * 196u;
          if (m < 8) {
            ((_Float16*)out1)[((size_t)m * 512 + s) * KP + p] = (_Float16)v;
          } else if (m < 392) {
            // fragment-major: kk=(m-8)>>6, frag=(p>>5)*4 + ((m-8)&63)>>4,
            // lane=((p>>3)&3)*16 + ((m-8)&15), elem=p&7
            const int mm = m - 8;
            const size_t idx =
              ((((size_t)s * 6 + (mm >> 6)) * 28 + (p >> 5) * 4 + ((mm & 63) >> 4)) * 64
               + ((p >> 3) & 3) * 16 + (mm & 15)) * 8 + (p & 7);
            ((_Float16*)out0)[idx] = (_Float16)v;
          } else if (m < 400) {
            ((_Float16*)out2)[((size_t)(m - 392) * 512 + s) * KP + p] = (_Float16)v;
          }
        } else if constexpr (MODE == 2) {
          if (n < 320)
            ((float*)out0)[(size_t)(m & 511) * 2560 + (m >> 9) * 320 + n] = v;
        } else {
          if (n < 32)
            ((float*)out0)[(size_t)m * 32 + n] = v;
        }
      }
    }
  }
}

// ---------------- fused chain kernel ----------------
__device__ __forceinline__ void stageA3(const _Float16* __restrict__ base,
                                        _Float16* __restrict__ ash, int tid) {
  const int wave = tid >> 6;
#pragma unroll
  for (int it = 0; it < 7; it++) {
    const int c = it * 256 + tid;   // 1792 chunks exactly, fully coalesced
    gld_lds16(base + (size_t)c * 8, (char*)ash + (size_t)(it * 256 + wave * 64) * 16);
  }
}

__global__ __launch_bounds__(256, 2)
void chain_kernel(const _Float16* __restrict__ Mt3, const _Float16* __restrict__ Akr,
                  const float* __restrict__ St0, const float* __restrict__ GN,
                  float* __restrict__ out)
{
  __shared__ __align__(16) _Float16 Ash[28 * 512];     // 28672 B, fragment-major
  __shared__ __align__(16) _Float16 Gsh[256 * GSTR2];  // 36864 B
  __shared__ __align__(16) _Float16 St3[16 * SSTR];    // 8448 B
  __shared__ float oc[10];

  const int tid  = threadIdx.x;
  const int wave = tid >> 6;
  const int lane = tid & 63;
  const int s    = blockIdx.x;
  const int fr   = lane & 15;
  const int fq   = lane >> 4;
  const int fqh  = fq >> 1;
  const int fql  = fq & 1;

  // init: St3[c][r*8+sigma(b)] from St0[s][b*320+r*10+c]; tid=(b,r)
  {
    const int b = tid >> 5, r = tid & 31;
    const int kcol = r * 8 + ((b & 1) * 4 + (b >> 1));
    const float* src = St0 + (size_t)s * 2560 + (size_t)tid * 10;
#pragma unroll
    for (int c = 0; c < 10; c++) St3[c * SSTR + kcol] = (_Float16)src[c];
    if (tid < 10) oc[tid] = 0.f;
  }
  stageA3(Mt3 + (size_t)s * 6 * SLICE, Ash, tid);
  __syncthreads();   // Ash (vmcnt drained) + St3 visible

  for (int k = 0; k < 6; k++) {
    floatx4 ns[4] = {};
    const _Float16* Bk = Akr + (size_t)k * 1024 * KP;

    for (int cc = 0; cc < 4; cc++) {
      // ---- G-phase: wave owns cols n = cc*256 + wave*64 + ni*16 + fr ----
      floatx4 acc[4][4] = {};
      const _Float16* Bb = Bk + (size_t)(cc * 256 + wave * 64) * KP;
      half8 bf[2][4];
#pragma unroll
      for (int ni = 0; ni < 4; ni++)
        bf[0][ni] = *(const half8*)(Bb + (size_t)(ni * 16 + fr) * KP + fq * 8);
#pragma unroll
      for (int kt = 0; kt < 7; kt++) {
        if (kt < 6) {   // rolling prefetch of next kt's B fragments
#pragma unroll
          for (int ni = 0; ni < 4; ni++)
            bf[(kt + 1) & 1][ni] =
              *(const half8*)(Bb + (size_t)(ni * 16 + fr) * KP + (kt + 1) * 32 + fq * 8);
        }
        half8 af[4];
#pragma unroll
        for (int mi = 0; mi < 4; mi++)   // lane-contiguous, conflict-free
          af[mi] = *(const half8*)&Ash[((kt * 4 + mi) * 64 + lane) * 8];
#pragma unroll
        for (int mi = 0; mi < 4; mi++)
#pragma unroll
          for (int ni = 0; ni < 4; ni++)
            acc[mi][ni] = __builtin_amdgcn_mfma_f32_16x16x32_f16(af[mi], bf[kt & 1][ni], acc[mi][ni], 0, 0, 0);
      }
      // cvt: pack 4 mi-values (k'-contiguous under sigma) per (ni,rg)
      half4 gh[4][4];
#pragma unroll
      for (int ni = 0; ni < 4; ni++)
#pragma unroll
        for (int rg = 0; rg < 4; rg++)
#pragma unroll
          for (int mi = 0; mi < 4; mi++)
            gh[ni][rg][mi] = (_Float16)acc[mi][ni][rg];
      // write Gsh: row m2=(b,r), k' = wave*16 + (ni>>1)*8 + fqh*4 + mi
#pragma unroll
      for (int ni = 0; ni < 4; ni++)
#pragma unroll
        for (int rg = 0; rg < 4; rg++) {
          const int m2 = (fql * 4 + rg) * 32 + (ni & 1) * 16 + fr;
          *(half4*)&Gsh[m2 * GSTR2 + wave * 16 + (ni >> 1) * 8 + fqh * 4] = gh[ni][rg];
        }
      __syncthreads();   // B1: Gsh visible; all waves past G-phase Ash reads
      if (cc == 3 && k < 5)   // restage next step's A during NS phase
        stageA3(Mt3 + ((size_t)s * 6 + k + 1) * SLICE, Ash, tid);
      // ---- NS-phase: NS[m2][c] += G[m2][k' 64-window] * St3[c][same] ----
#pragma unroll
      for (int kk = 0; kk < 2; kk++) {
        const half8 bs = *(const half8*)&St3[fr * SSTR + cc * 64 + kk * 32 + fq * 8];
#pragma unroll
        for (int t = 0; t < 4; t++) {
          const half8 aa = *(const half8*)&Gsh[((wave * 4 + t) * 16 + fr) * GSTR2 + kk * 32 + fq * 8];
          ns[t] = __builtin_amdgcn_mfma_f32_16x16x32_f16(aa, bs, ns[t], 0, 0, 0);
        }
      }
      __syncthreads();   // B2: NS reads done before next cc overwrites Gsh
    }

    // epilogue: NS -> St3 (next step's B operand). m2=(b,r): k_next = r*8+sigma(b)
    if (fr < 10) {
#pragma unroll
      for (int t = 0; t < 4; t++) {
#pragma unroll
        for (int rg = 0; rg < 4; rg++) {
          const int m = (wave * 4 + t) * 16 + fq * 4 + rg;
          const int b = m >> 5, r = m & 31;
          St3[fr * SSTR + r * 8 + ((b & 1) * 4 + (b >> 1))] = (_Float16)ns[t][rg];
        }
      }
    }
    // next cc0's B1 orders these writes before any NS read; B2 drains stageA3
  }
  __syncthreads();

  // final: out[s,c] = sum_{a,l} St3[c][l*8+sigma(a)] * GN[a][s][l]
  {
    const int a = tid >> 5, l = tid & 31;
    const float gn = GN[((size_t)a * 512 + s) * 32 + l];
    const int kcol = l * 8 + ((a & 1) * 4 + (a >> 1));
#pragma unroll
    for (int c = 0; c < 10; c++) {
      float v = gn * (float)St3[c * SSTR + kcol];
#pragma unroll
      for (int o2 = 1; o2 < 64; o2 <<= 1) v += __shfl_xor(v, o2, 64);
      if (lane == 0) atomicAdd(&oc[c], v);
    }
    __syncthreads();
    if (tid < 10) out[(size_t)s * 10 + tid] = oc[tid];
  }
}

// ---------------- prep kernels ----------------
__global__ void prep_xh(const float* __restrict__ x, _Float16* __restrict__ xh) {
  const int idx = blockIdx.x * 256 + threadIdx.x;
  const int q = idx & 63, sp = idx >> 6;
  xh[idx] = (q < 48) ? (_Float16)x[sp * 48 + q] : (_Float16)0.f;
}

__global__ void prep_small(const float* __restrict__ cf, const float* __restrict__ cm,
                           const float* __restrict__ cl, const float* __restrict__ tf,
                           const float* __restrict__ tm, const float* __restrict__ tl,
                           _Float16* __restrict__ Ckt, _Float16* __restrict__ Akr,
                           _Float16* __restrict__ Bt0, _Float16* __restrict__ Btl) {
  const int idx = blockIdx.x * 256 + threadIdx.x;
  if (idx < 32768) {
    const int q = idx & 63;
    const int row = idx >> 6;
    float v = 0.f;
    if (q < 48) {
      if (row < 8) v = cf[q * 8 + row];
      else if (row < 392) {
        const int rr = row - 8;
        const int k = rr >> 6, ab = rr & 63, a = ab >> 3, b = ab & 7;
        v = cm[((k * 8 + a) * 48 + q) * 8 + b];
      } else if (row < 400) v = cl[(row - 392) * 48 + q];
    }
    Ckt[idx] = (_Float16)v;
  } else if (idx < 1409024) {
    const int i2 = idx - 32768;
    const int p = i2 % 224;
    const int lr = (i2 / 224) & 1023;
    const int k = i2 / (224 * 1024);
    const int l = lr >> 5, r = lr & 31;
    float v = 0.f;
    if (p < 196) v = tm[(((k * 32 + l) * 196) + p) * 32 + r];
    Akr[i2] = (_Float16)v;
  } else if (idx < 1495040) {
    const int i2 = idx - 1409024;
    const int p = i2 % 224;
    const int n = i2 / 224;
    float v = 0.f;
    if (n < 320 && p < 196) {
      const int r = n / 10, c = n % 10;
      v = tf[(c * 196 + p) * 32 + r];
    }
    Bt0[i2] = (_Float16)v;
  } else {
    const int i2 = idx - 1495040;
    const int p = i2 % 224;
    const int n = i2 / 224;
    float v = 0.f;
    if (n < 32 && p < 196) v = tl[n * 196 + p];
    Btl[i2] = (_Float16)v;
  }
}

// zero pad regions: Mt3 kt=6 fragments (frags 24..27 per (s,k)) + MtF/MtL col pads
__global__ void zero_pads(_Float16* __restrict__ Mt3, _Float16* __restrict__ MtF,
                          _Float16* __restrict__ MtL) {
  const int idx = blockIdx.x * 256 + threadIdx.x;   // 768*256 = 196608
  if (idx < 196608) {
    const int s6 = idx >> 6, lane = idx & 63;       // s6 in [0,3072)
    const int4 z = {0, 0, 0, 0};
#pragma unroll
    for (int mi = 0; mi < 4; mi++)
      *(int4*)&Mt3[(((size_t)s6 * 28 + 24 + mi) * 64 + lane) * 8] = z;
  }
  if (idx < 4096) {
    _Float16* p = MtF + (size_t)idx * KP + 196;
    _Float16* q = MtL + (size_t)idx * KP + 196;
#pragma unroll
    for (int j = 0; j < 28; j++) { p[j] = (_Float16)0.f; q[j] = (_Float16)0.f; }
  }
}

extern "C" void kernel_launch(void* const* d_in, const int* in_sizes, int n_in,
                              void* d_out, int out_size, void* d_ws, size_t ws_size,
                              hipStream_t stream)
{
  const float* x  = (const float*)d_in[0];
  const float* cf = (const float*)d_in[1];
  const float* cm = (const float*)d_in[2];
  const float* cl = (const float*)d_in[3];
  const float* tf = (const float*)d_in[4];
  const float* tm = (const float*)d_in[5];
  const float* tl = (const float*)d_in[6];
  float* out = (float*)d_out;

  char* w = (char*)d_ws;
  auto alloc = [&](size_t bytes) { char* p = w; w += (bytes + 255) & ~(size_t)255; return p; };
  _Float16* xh  = (_Float16*)alloc(100352ull * 64 * 2);      // 12.8 MB
  _Float16* Ckt = (_Float16*)alloc(512ull * 64 * 2);
  _Float16* Mt3 = (_Float16*)alloc(512ull * 6 * SLICE * 2);  // 88.1 MB fragment-major
  _Float16* MtF = (_Float16*)alloc(8ull * 512 * KP * 2);
  _Float16* MtL = (_Float16*)alloc(8ull * 512 * KP * 2);
  _Float16* Akr = (_Float16*)alloc(6ull * 1024 * KP * 2);    // 2.75 MB
  _Float16* Bt0 = (_Float16*)alloc(384ull * KP * 2);
  _Float16* Btl = (_Float16*)alloc(128ull * KP * 2);
  float* stA    = (float*)alloc(512ull * 2560 * 4);
  float* GN     = (float*)alloc(4096ull * 32 * 4);
  (void)ws_size; (void)in_sizes; (void)n_in; (void)out_size;

  prep_xh   <<<25088, 256, 0, stream>>>(x, xh);
  prep_small<<< 5952, 256, 0, stream>>>(cf, cm, cl, tf, tm, tl, Ckt, Akr, Bt0, Btl);
  zero_pads <<<  768, 256, 0, stream>>>(Mt3, MtF, MtL);

  gemm_mfma<QP, 0><<<dim3(784, 4), 256, 0, stream>>>(Ckt, xh, Mt3, MtF, MtL);
  gemm_mfma<KP, 2><<<dim3(3, 32), 256, 0, stream>>>(MtF, Bt0, stA, nullptr, nullptr);
  gemm_mfma<KP, 3><<<dim3(1, 32), 256, 0, stream>>>(MtL, Btl, GN, nullptr, nullptr);

  chain_kernel<<<512, 256, 0, stream>>>(Mt3, Akr, stA, GN, out);
}